// Round 11
// baseline (284.239 us; speedup 1.0000x reference)
//
#include <hip/hip_runtime.h>
#include <hip/hip_bf16.h>
#include <stdint.h>
#include <stddef.h>

#define NH 12
#define DKH 64
#define DM 768
#define SS 4096

typedef __attribute__((ext_vector_type(8))) short bf16x8;
typedef __attribute__((ext_vector_type(4))) float f32x4;
typedef __attribute__((ext_vector_type(16))) float f32x16;

__device__ __forceinline__ unsigned short f2bf(float x) {
  union { float f; unsigned int u; } a; a.f = x;
  unsigned int r = a.u + 0x7fffu + ((a.u >> 16) & 1u);
  return (unsigned short)(r >> 16);
}

__device__ __forceinline__ unsigned pkbf2(float a, float b) {
  union { __hip_bfloat162 h; unsigned u; } x;
  x.h = __float22bfloat162_rn(float2{a, b});
  return x.u;
}

__device__ __forceinline__ unsigned cvt_pk_bf16(float lo, float hi) {
  unsigned r;
  asm("v_cvt_pk_bf16_f32 %0, %1, %2" : "=v"(r) : "v"(lo), "v"(hi));
  return r;
}

__device__ __forceinline__ void plane32_swap(unsigned& a, unsigned& b) {
  asm("v_permlane32_swap_b32 %0, %1" : "+v"(a), "+v"(b));
}

__device__ __forceinline__ float fast_exp2(float x) {
#if __has_builtin(__builtin_amdgcn_exp2f)
  return __builtin_amdgcn_exp2f(x);
#else
  return exp2f(x);
#endif
}

// global -> LDS async 16B/lane. LDS dest is wave-uniform base + lane*16.
__device__ __forceinline__ void gload16(const void* g, void* l) {
  __builtin_amdgcn_global_load_lds(
      (const __attribute__((address_space(1))) void*)g,
      (__attribute__((address_space(3))) void*)l, 16, 0, 0);
}

// ---------------------------------------------------------------------------
// Prep kernel: qkv fp32->bf16 (blocks 0..9215) + weight repack (9216..11519).
// wq gets Q-scale 0.125*log2e folded in.
// ---------------------------------------------------------------------------
__global__ __launch_bounds__(256) void prep(
    const float* __restrict__ Q, const float* __restrict__ K,
    const float* __restrict__ V, const float* __restrict__ WQ,
    const float* __restrict__ WK, const float* __restrict__ WV,
    const float* __restrict__ WO, unsigned short* __restrict__ qkv,
    unsigned short* __restrict__ wq, unsigned short* __restrict__ wk,
    unsigned short* __restrict__ wv, unsigned short* __restrict__ wo) {
  int bx = blockIdx.x;
  if (bx < 9216) {
    int gid = bx * 256 + threadIdx.x;
    int t = gid / 786432, e = gid % 786432;
    const float* src = (t == 0) ? Q : (t == 1) ? K : V;
    float4 a = *(const float4*)(src + (size_t)e * 8);
    float4 c = *(const float4*)(src + (size_t)e * 8 + 4);
    union { unsigned u[4]; uint4 v; } o;
    o.u[0] = pkbf2(a.x, a.y); o.u[1] = pkbf2(a.z, a.w);
    o.u[2] = pkbf2(c.x, c.y); o.u[3] = pkbf2(c.z, c.w);
    *(uint4*)(qkv + (size_t)t * 6291456 + (size_t)e * 8) = o.v;
  } else {
    int idx = (bx - 9216) * 256 + threadIdx.x;
    if (idx >= DM * DM) return;
    int n = idx / DM, k = idx % DM;
    int src = ((n >> 6) * DM + k) * DKH + (n & 63);
    wq[idx] = f2bf(WQ[src] * 0.18033688011112042f);
    wk[idx] = f2bf(WK[src]);
    wv[idx] = f2bf(WV[src]);
    wo[idx] = f2bf(WO[k * DM + n]);
  }
}

// ---------------------------------------------------------------------------
// Merged projection GEMM (unchanged from round 10).
// ---------------------------------------------------------------------------
__global__ __launch_bounds__(256, 2) void proj_gemm3(
    const unsigned short* __restrict__ Abase,
    const unsigned short* __restrict__ Wbase,
    unsigned short* __restrict__ Obase) {
  __shared__ unsigned short As[2][128 * 64];
  __shared__ unsigned short Bs[2][96 * 64];
  const int tid = threadIdx.x;
  const int lane = tid & 63, wave = tid >> 6;
  const int wm = wave >> 1, wn = wave & 1;
  const int l15 = lane & 15, lhi = lane >> 4;
  const int lrow = lane >> 3;
  const int schunk = (lane & 7) ^ lrow;

  int fid = blockIdx.x + (blockIdx.y << 3) + (blockIdx.z << 9);
  int nid = (fid & 7) * 192 + (fid >> 3);
  const int bx = nid & 7;
  const int rem = nid >> 3;
  const int by = rem & 63, z = rem >> 6;
  const bool z2 = (z == 2);

  const unsigned short* A = Abase + (size_t)z * 6291456;
  const unsigned short* Wt = Wbase + (size_t)z * DM * DM;
  unsigned short* out = Obase + (size_t)z * 2 * NH * SS * DKH;
  const int m0 = by * 128, n0 = bx * 96;

  auto stage = [&](int k0, int buf) {
#pragma unroll
    for (int i = 0; i < 4; ++i) {
      int r = wave * 32 + i * 8;
      gload16(A + (size_t)(m0 + r + lrow) * DM + k0 + schunk * 8, &As[buf][r * 64]);
    }
#pragma unroll
    for (int i = 0; i < 3; ++i) {
      int r = wave * 24 + i * 8;
      gload16(Wt + (size_t)(n0 + r + lrow) * DM + k0 + schunk * 8, &Bs[buf][r * 64]);
    }
  };

  f32x4 acc[4][3] = {};

  stage(0, 0);
  stage(64, 1);

  for (int t = 0; t < 12; ++t) {
    if (t < 11) asm volatile("s_waitcnt vmcnt(7)" ::: "memory");
    else        asm volatile("s_waitcnt vmcnt(0)" ::: "memory");
    asm volatile("s_barrier" ::: "memory");
    const int buf = t & 1;
    bf16x8 af[4][2], bfr[3][2];
#pragma unroll
    for (int m = 0; m < 4; ++m) {
      int row = wm * 64 + m * 16 + l15;
#pragma unroll
      for (int ks = 0; ks < 2; ++ks)
        af[m][ks] = *(const bf16x8*)&As[buf][row * 64 + (((ks * 4 + lhi) ^ (row & 7)) * 8)];
    }
#pragma unroll
    for (int n = 0; n < 3; ++n) {
      int row = wn * 48 + n * 16 + l15;
#pragma unroll
      for (int ks = 0; ks < 2; ++ks)
        bfr[n][ks] = *(const bf16x8*)&Bs[buf][row * 64 + (((ks * 4 + lhi) ^ (row & 7)) * 8)];
    }
    asm volatile("s_waitcnt lgkmcnt(0)" ::: "memory");
    asm volatile("s_barrier" ::: "memory");
    if (t + 2 < 12) stage((t + 2) * 64, buf);
    __builtin_amdgcn_s_setprio(1);
#pragma unroll
    for (int ks = 0; ks < 2; ++ks)
#pragma unroll
      for (int m = 0; m < 4; ++m)
#pragma unroll
        for (int n = 0; n < 3; ++n) {
          if (z2)
            acc[m][n] = __builtin_amdgcn_mfma_f32_16x16x32_bf16(bfr[n][ks], af[m][ks], acc[m][n], 0, 0, 0);
          else
            acc[m][n] = __builtin_amdgcn_mfma_f32_16x16x32_bf16(af[m][ks], bfr[n][ks], acc[m][n], 0, 0, 0);
        }
    __builtin_amdgcn_s_setprio(0);
  }

  if (!z2) {
#pragma unroll
    for (int m = 0; m < 4; ++m) {
#pragma unroll
      for (int r = 0; r < 4; ++r) {
        int row = m0 + wm * 64 + m * 16 + lhi * 4 + r;
        int bb = row >> 12, s = row & 4095;
#pragma unroll
        for (int n = 0; n < 3; ++n) {
          int col = n0 + wn * 48 + n * 16 + l15;
          int hh = col >> 6, dk = col & 63;
          out[((size_t)(bb * NH + hh) * SS + s) * DKH + dk] = f2bf(acc[m][n][r]);
        }
      }
    }
  } else {
#pragma unroll
    for (int m = 0; m < 4; ++m) {
      int srow = m0 + wm * 64 + m * 16 + l15;
      int bb = srow >> 12, s = srow & 4095;
#pragma unroll
      for (int n = 0; n < 3; ++n) {
#pragma unroll
        for (int r = 0; r < 4; ++r) {
          int col = n0 + wn * 48 + n * 16 + lhi * 4 + r;
          int hh = col >> 6, dk = col & 63;
          out[((size_t)(bb * NH + hh) * DKH + dk) * SS + s] = f2bf(acc[m][n][r]);
        }
      }
    }
  }
}

// ---------------------------------------------------------------------------
// pack 32 f32 P-values into 4 PV B-fragments (proven mapping)
// ---------------------------------------------------------------------------
__device__ __forceinline__ void pack_pb(const f32x16& s0, const f32x16& s1, bf16x8* pb) {
#pragma unroll
  for (int h2 = 0; h2 < 2; ++h2) {
    unsigned c0a = cvt_pk_bf16(s0[8 * h2 + 0], s0[8 * h2 + 1]);
    unsigned c1a = cvt_pk_bf16(s0[8 * h2 + 2], s0[8 * h2 + 3]);
    unsigned c0b = cvt_pk_bf16(s0[8 * h2 + 4], s0[8 * h2 + 5]);
    unsigned c1b = cvt_pk_bf16(s0[8 * h2 + 6], s0[8 * h2 + 7]);
    plane32_swap(c0a, c0b);
    plane32_swap(c1a, c1b);
    union { unsigned u[4]; bf16x8 v; } f;
    f.u[0] = c0a; f.u[1] = c1a; f.u[2] = c0b; f.u[3] = c1b;
    pb[h2] = f.v;
  }
#pragma unroll
  for (int h2 = 0; h2 < 2; ++h2) {
    unsigned c0a = cvt_pk_bf16(s1[8 * h2 + 0], s1[8 * h2 + 1]);
    unsigned c1a = cvt_pk_bf16(s1[8 * h2 + 2], s1[8 * h2 + 3]);
    unsigned c0b = cvt_pk_bf16(s1[8 * h2 + 4], s1[8 * h2 + 5]);
    unsigned c1b = cvt_pk_bf16(s1[8 * h2 + 6], s1[8 * h2 + 7]);
    plane32_swap(c0a, c0b);
    plane32_swap(c1a, c1b);
    union { unsigned u[4]; bf16x8 v; } f;
    f.u[0] = c0a; f.u[1] = c1a; f.u[2] = c0b; f.u[3] = c1b;
    pb[2 + h2] = f.v;
  }
}

__device__ __forceinline__ float tree16(const f32x16& v) {
  float a = (v[0] + v[1]) + (v[2] + v[3]);
  float b = (v[4] + v[5]) + (v[6] + v[7]);
  float c = (v[8] + v[9]) + (v[10] + v[11]);
  float d = (v[12] + v[13]) + (v[14] + v[15]);
  return (a + b) + (c + d);
}

// ---------------------------------------------------------------------------
// Flash attention v11: 32q/wave, K-direct from global, V-only LDS.
// Block = 4 waves x 32q = 128 q, full-KV sweep (no combine epilogue).
// K: per-lane A-fragments loaded global->reg (r7/r9-proven mapping), single
//    register set, reload pinned between sched_barriers right after QK.
// V: one shared 8 KB tile (all 4 waves), staged via gload16 (2/wave),
//    single-buffered with counted vmcnt: pre-PV vmcnt(8) leaves K(t+1)'s
//    8 loads in flight. 2 barriers/iter. State ~130 regs -> (256,3) cap
//    168 -> 3 waves/SIMD, 12 waves/CU (vs 8 for all 64q variants).
// grid (32,24)=768 = 3 blocks/CU exactly one round; XCD swizzle -> 3 bh
// (3 MB K+V) per XCD L2.
// ---------------------------------------------------------------------------
__global__ __launch_bounds__(256, 3) void flash_attn(
    const unsigned short* __restrict__ Qp, const unsigned short* __restrict__ Kp,
    const unsigned short* __restrict__ Vt, unsigned short* __restrict__ Ao) {
  __shared__ unsigned short Vs[4096];  // V tile [64 d][64 kv], 8 KB, shared
  const int tid = threadIdx.x;
  const int lane = tid & 63, wave = tid >> 6;
  const int ql = lane & 31, hi = lane >> 5;

  int fid = blockIdx.x + (blockIdx.y << 5);
  int nid = (fid & 7) * 96 + (fid >> 3);
  const int bx = nid & 31, bh = nid >> 5;
  const int b = bh / NH, h = bh % NH;
  const int q0w = bx * 128 + wave * 32;

  // Q B-fragments (col=q=ql): 16 VGPR
  bf16x8 qf[4];
  {
    const unsigned short* qb = Qp + ((size_t)bh * SS + q0w + ql) * DKH;
#pragma unroll
    for (int s = 0; s < 4; ++s)
      qf[s] = *(const bf16x8*)(qb + s * 16 + hi * 8);
  }

  const unsigned short* gK = Kp + (size_t)bh * SS * DKH;
  const unsigned short* gV = Vt + (size_t)bh * DKH * SS;
  const int lrow = lane >> 3;
  const int sch = ((lane & 7) ^ lrow) * 8;  // pre-swizzled source chunk (V)
  const int xs = (ql & 7) << 3;             // read-side swizzle (V)
  const unsigned short* pkb = gK + (size_t)ql * DKH + hi * 8;

  // K A-fragments, single set (32 VGPR), reloaded in place each iter
  bf16x8 kf0[4], kf1[4];
  auto loadK = [&](int kv0) {
    const unsigned short* pk = pkb + (size_t)kv0 * DKH;
#pragma unroll
    for (int s = 0; s < 4; ++s) {
      kf0[s] = *(const bf16x8*)(pk + s * 16);         // kv rows kv0+ql(+0)
      kf1[s] = *(const bf16x8*)(pk + 2048 + s * 16);  // kv rows kv0+32+ql
    }
  };
  auto stageV = [&](int kv0) {
#pragma unroll
    for (int i = 0; i < 2; ++i) {
      int r = wave * 16 + i * 8;
      gload16(gV + (size_t)(r + lrow) * SS + kv0 + sch, &Vs[r * 64]);
    }
  };

  loadK(0);   // 8 vmem (register-dest)
  stageV(0);  // 2 vmem (LDS-dest)

  f32x16 oA = {}, oB = {};
  float lp = 0.f;
  const f32x16 zc = {};

  for (int it = 0; it < 64; ++it) {
    const bool notlast = (it < 63);
    // compiler auto-inserts vmcnt for kf register deps before first use
    f32x16 s0, s1;
    __builtin_amdgcn_s_setprio(1);
    s0 = __builtin_amdgcn_mfma_f32_32x32x16_bf16(kf0[0], qf[0], zc, 0, 0, 0);
    s1 = __builtin_amdgcn_mfma_f32_32x32x16_bf16(kf1[0], qf[0], zc, 0, 0, 0);
#pragma unroll
    for (int s = 1; s < 4; ++s) {
      s0 = __builtin_amdgcn_mfma_f32_32x32x16_bf16(kf0[s], qf[s], s0, 0, 0, 0);
      s1 = __builtin_amdgcn_mfma_f32_32x32x16_bf16(kf1[s], qf[s], s1, 0, 0, 0);
    }
    __builtin_amdgcn_s_setprio(0);
    __builtin_amdgcn_sched_barrier(0);  // QK consumed kf; now reload in place
    if (notlast) loadK((it + 1) * 64);  // 8 loads, pinned here
    __builtin_amdgcn_sched_barrier(0);

    // P = exp2(S) (scores bounded; exp2-domain folded into wq) + row partial
#pragma unroll
    for (int r = 0; r < 16; ++r) s0[r] = fast_exp2(s0[r]);
#pragma unroll
    for (int r = 0; r < 16; ++r) s1[r] = fast_exp2(s1[r]);
    lp += tree16(s0) + tree16(s1);

    bf16x8 pb[4];
    pack_pb(s0, s1, pb);

    // V(it) landed (its 2 gloads are the oldest); K(it+1)'s 8 still fly
    if (notlast) asm volatile("s_waitcnt vmcnt(8)" ::: "memory");
    else         asm volatile("s_waitcnt vmcnt(0)" ::: "memory");
    asm volatile("s_barrier" ::: "memory");
    __builtin_amdgcn_sched_barrier(0);

    __builtin_amdgcn_s_setprio(1);
#pragma unroll
    for (int ks = 0; ks < 4; ++ks) {
      bf16x8 va0 = *(const bf16x8*)&Vs[ql * 64 + ((ks * 16 + hi * 8) ^ xs)];
      bf16x8 va1 = *(const bf16x8*)&Vs[(32 + ql) * 64 + ((ks * 16 + hi * 8) ^ xs)];
      oA = __builtin_amdgcn_mfma_f32_32x32x16_bf16(va0, pb[ks], oA, 0, 0, 0);
      oB = __builtin_amdgcn_mfma_f32_32x32x16_bf16(va1, pb[ks], oB, 0, 0, 0);
    }
    __builtin_amdgcn_s_setprio(0);

    if (notlast) {
      asm volatile("s_waitcnt lgkmcnt(0)" ::: "memory");  // own V reads retired
      asm volatile("s_barrier" ::: "memory");             // all waves done with V(it)
      stageV((it + 1) * 64);
    }
  }

  // epilogue: direct normalize + store
  float inv = 1.0f / (lp + __shfl_xor(lp, 32));
  unsigned short* orow = Ao + ((size_t)b * SS + q0w + ql) * DM + h * DKH;
#pragma unroll
  for (int g = 0; g < 4; ++g) {
    int d0 = g * 8 + hi * 4;
    *(unsigned*)&orow[d0]          = cvt_pk_bf16(oA[4 * g + 0] * inv, oA[4 * g + 1] * inv);
    *(unsigned*)&orow[d0 + 2]      = cvt_pk_bf16(oA[4 * g + 2] * inv, oA[4 * g + 3] * inv);
    *(unsigned*)&orow[32 + d0]     = cvt_pk_bf16(oB[4 * g + 0] * inv, oB[4 * g + 1] * inv);
    *(unsigned*)&orow[32 + d0 + 2] = cvt_pk_bf16(oB[4 * g + 2] * inv, oB[4 * g + 3] * inv);
  }
}

// ---------------------------------------------------------------------------
// Output GEMM (unchanged from round 10).
// ---------------------------------------------------------------------------
__global__ __launch_bounds__(256, 2) void out_gemm(
    const unsigned short* __restrict__ A, const unsigned short* __restrict__ Wt,
    float* __restrict__ out) {
  __shared__ unsigned short As[2][64 * 64];
  __shared__ unsigned short Bs[2][128 * 64];
  const int tid = threadIdx.x;
  const int lane = tid & 63, wave = tid >> 6;
  const int wm = wave >> 1, wn = wave & 1;
  const int l15 = lane & 15, lhi = lane >> 4;
  const int lrow = lane >> 3;
  const int schunk = (lane & 7) ^ lrow;

  int fid = blockIdx.x + 6 * blockIdx.y;
  int nid = (fid & 7) * 96 + (fid >> 3);
  const int bx = nid % 6, by = nid / 6;
  const int m0 = by * 64, n0 = bx * 128;

  auto stage = [&](int k0, int buf) {
#pragma unroll
    for (int i = 0; i < 4; ++i) {
      int r = wave * 32 + i * 8;
      gload16(Wt + (size_t)(n0 + r + lrow) * DM + k0 + schunk * 8, &Bs[buf][r * 64]);
    }
#pragma unroll
    for (int i = 0; i < 2; ++i) {
      int r = wave * 16 + i * 8;
      gload16(A + (size_t)(m0 + r + lrow) * DM + k0 + schunk * 8, &As[buf][r * 64]);
    }
  };

  f32x4 acc[2][4] = {};
  stage(0, 0);
  stage(64, 1);

  for (int t = 0; t < 12; ++t) {
    if (t < 11) asm volatile("s_waitcnt vmcnt(6)" ::: "memory");
    else        asm volatile("s_waitcnt vmcnt(0)" ::: "memory");
    asm volatile("s_barrier" ::: "memory");
    const int buf = t & 1;
    bf16x8 af[2][2], bfr[4][2];
#pragma unroll
    for (int m = 0; m < 2; ++m) {
      int row = wm * 32 + m * 16 + l15;
#pragma unroll
      for (int ks = 0; ks < 2; ++ks)
        af[m][ks] = *(const bf16x8*)&As[buf][row * 64 + (((ks * 4 + lhi) ^ (row & 7)) * 8)];
    }
#pragma unroll
    for (int n = 0; n < 4; ++n) {
      int row = wn * 64 + n * 16 + l15;
#pragma unroll
      for (int ks = 0; ks < 2; ++ks)
        bfr[n][ks] = *(const bf16x8*)&Bs[buf][row * 64 + (((ks * 4 + lhi) ^ (row & 7)) * 8)];
    }
    asm volatile("s_waitcnt lgkmcnt(0)" ::: "memory");
    asm volatile("s_barrier" ::: "memory");
    if (t + 2 < 12) stage((t + 2) * 64, buf);
    __builtin_amdgcn_s_setprio(1);
#pragma unroll
    for (int ks = 0; ks < 2; ++ks)
#pragma unroll
      for (int m = 0; m < 2; ++m)
#pragma unroll
        for (int n = 0; n < 4; ++n)
          acc[m][n] = __builtin_amdgcn_mfma_f32_16x16x32_bf16(af[m][ks], bfr[n][ks], acc[m][n], 0, 0, 0);
    __builtin_amdgcn_s_setprio(0);
  }

#pragma unroll
  for (int m = 0; m < 2; ++m)
#pragma unroll
    for (int r = 0; r < 4; ++r) {
      int row = m0 + wm * 32 + m * 16 + lhi * 4 + r;
#pragma unroll
      for (int n = 0; n < 4; ++n) {
        int col = n0 + wn * 64 + n * 16 + l15;
        out[(size_t)row * DM + col] = acc[m][n][r];
      }
    }
}

// ---------------------------------------------------------------------------
extern "C" void kernel_launch(void* const* d_in, const int* in_sizes, int n_in,
                              void* d_out, int out_size, void* d_ws, size_t ws_size,
                              hipStream_t stream) {
  const float* Q  = (const float*)d_in[0];
  const float* K  = (const float*)d_in[1];
  const float* V  = (const float*)d_in[2];
  const float* WQ = (const float*)d_in[3];
  const float* WK = (const float*)d_in[4];
  const float* WV = (const float*)d_in[5];
  const float* WO = (const float*)d_in[6];
  char* ws = (char*)d_ws;

  const size_t WSZ = (size_t)DM * DM * 2;
  const size_t ABF = (size_t)2 * SS * DM * 2;
  unsigned short* w_base  = (unsigned short*)(ws);
  unsigned short* wo_t    = (unsigned short*)(ws + 3 * WSZ);
  unsigned short* qkv_bf  = (unsigned short*)(ws + 4 * WSZ);
  unsigned short* p_base  = (unsigned short*)(ws + 4 * WSZ + 3 * ABF);
  unsigned short* q_p  = p_base;
  unsigned short* k_p  = p_base + ABF / 2;
  unsigned short* v_t  = p_base + ABF;
  unsigned short* attn = p_base + 3 * (ABF / 2);

  prep<<<9216 + 2304, 256, 0, stream>>>(
      Q, K, V, WQ, WK, WV, WO, qkv_bf,
      w_base, w_base + WSZ / 2, w_base + WSZ, wo_t);

  proj_gemm3<<<dim3(8, 64, 3), 256, 0, stream>>>(qkv_bf, w_base, p_base);

  flash_attn<<<dim3(32, 24), 256, 0, stream>>>(q_p, k_p, v_t, attn);

  out_gemm<<<dim3(6, 128), 256, 0, stream>>>(attn, wo_t, (float*)d_out);
}

// Round 12
// 215.172 us; speedup vs baseline: 1.3210x; 1.3210x over previous
//
#include <hip/hip_runtime.h>
#include <hip/hip_bf16.h>
#include <stdint.h>
#include <stddef.h>

#define NH 12
#define DKH 64
#define DM 768
#define SS 4096

typedef __attribute__((ext_vector_type(8))) short bf16x8;
typedef __attribute__((ext_vector_type(4))) float f32x4;
typedef __attribute__((ext_vector_type(16))) float f32x16;

__device__ __forceinline__ unsigned short f2bf(float x) {
  union { float f; unsigned int u; } a; a.f = x;
  unsigned int r = a.u + 0x7fffu + ((a.u >> 16) & 1u);
  return (unsigned short)(r >> 16);
}

__device__ __forceinline__ unsigned pkbf2(float a, float b) {
  union { __hip_bfloat162 h; unsigned u; } x;
  x.h = __float22bfloat162_rn(float2{a, b});
  return x.u;
}

__device__ __forceinline__ unsigned cvt_pk_bf16(float lo, float hi) {
  unsigned r;
  asm("v_cvt_pk_bf16_f32 %0, %1, %2" : "=v"(r) : "v"(lo), "v"(hi));
  return r;
}

__device__ __forceinline__ void plane32_swap(unsigned& a, unsigned& b) {
  asm("v_permlane32_swap_b32 %0, %1" : "+v"(a), "+v"(b));
}

__device__ __forceinline__ float fast_exp2(float x) {
#if __has_builtin(__builtin_amdgcn_exp2f)
  return __builtin_amdgcn_exp2f(x);
#else
  return exp2f(x);
#endif
}

// global -> LDS async 16B/lane. LDS dest is wave-uniform base + lane*16.
__device__ __forceinline__ void gload16(const void* g, void* l) {
  __builtin_amdgcn_global_load_lds(
      (const __attribute__((address_space(1))) void*)g,
      (__attribute__((address_space(3))) void*)l, 16, 0, 0);
}

// ---------------------------------------------------------------------------
// Prep kernel: qkv fp32->bf16 (blocks 0..9215) + weight repack (9216..11519).
// wq gets Q-scale 0.125*log2e folded in.
// ---------------------------------------------------------------------------
__global__ __launch_bounds__(256) void prep(
    const float* __restrict__ Q, const float* __restrict__ K,
    const float* __restrict__ V, const float* __restrict__ WQ,
    const float* __restrict__ WK, const float* __restrict__ WV,
    const float* __restrict__ WO, unsigned short* __restrict__ qkv,
    unsigned short* __restrict__ wq, unsigned short* __restrict__ wk,
    unsigned short* __restrict__ wv, unsigned short* __restrict__ wo) {
  int bx = blockIdx.x;
  if (bx < 9216) {
    int gid = bx * 256 + threadIdx.x;
    int t = gid / 786432, e = gid % 786432;
    const float* src = (t == 0) ? Q : (t == 1) ? K : V;
    float4 a = *(const float4*)(src + (size_t)e * 8);
    float4 c = *(const float4*)(src + (size_t)e * 8 + 4);
    union { unsigned u[4]; uint4 v; } o;
    o.u[0] = pkbf2(a.x, a.y); o.u[1] = pkbf2(a.z, a.w);
    o.u[2] = pkbf2(c.x, c.y); o.u[3] = pkbf2(c.z, c.w);
    *(uint4*)(qkv + (size_t)t * 6291456 + (size_t)e * 8) = o.v;
  } else {
    int idx = (bx - 9216) * 256 + threadIdx.x;
    if (idx >= DM * DM) return;
    int n = idx / DM, k = idx % DM;
    int src = ((n >> 6) * DM + k) * DKH + (n & 63);
    wq[idx] = f2bf(WQ[src] * 0.18033688011112042f);
    wk[idx] = f2bf(WK[src]);
    wv[idx] = f2bf(WV[src]);
    wo[idx] = f2bf(WO[k * DM + n]);
  }
}

// ---------------------------------------------------------------------------
// Merged projection GEMM (unchanged, proven).
// ---------------------------------------------------------------------------
__global__ __launch_bounds__(256, 2) void proj_gemm3(
    const unsigned short* __restrict__ Abase,
    const unsigned short* __restrict__ Wbase,
    unsigned short* __restrict__ Obase) {
  __shared__ unsigned short As[2][128 * 64];
  __shared__ unsigned short Bs[2][96 * 64];
  const int tid = threadIdx.x;
  const int lane = tid & 63, wave = tid >> 6;
  const int wm = wave >> 1, wn = wave & 1;
  const int l15 = lane & 15, lhi = lane >> 4;
  const int lrow = lane >> 3;
  const int schunk = (lane & 7) ^ lrow;

  int fid = blockIdx.x + (blockIdx.y << 3) + (blockIdx.z << 9);
  int nid = (fid & 7) * 192 + (fid >> 3);
  const int bx = nid & 7;
  const int rem = nid >> 3;
  const int by = rem & 63, z = rem >> 6;
  const bool z2 = (z == 2);

  const unsigned short* A = Abase + (size_t)z * 6291456;
  const unsigned short* Wt = Wbase + (size_t)z * DM * DM;
  unsigned short* out = Obase + (size_t)z * 2 * NH * SS * DKH;
  const int m0 = by * 128, n0 = bx * 96;

  auto stage = [&](int k0, int buf) {
#pragma unroll
    for (int i = 0; i < 4; ++i) {
      int r = wave * 32 + i * 8;
      gload16(A + (size_t)(m0 + r + lrow) * DM + k0 + schunk * 8, &As[buf][r * 64]);
    }
#pragma unroll
    for (int i = 0; i < 3; ++i) {
      int r = wave * 24 + i * 8;
      gload16(Wt + (size_t)(n0 + r + lrow) * DM + k0 + schunk * 8, &Bs[buf][r * 64]);
    }
  };

  f32x4 acc[4][3] = {};

  stage(0, 0);
  stage(64, 1);

  for (int t = 0; t < 12; ++t) {
    if (t < 11) asm volatile("s_waitcnt vmcnt(7)" ::: "memory");
    else        asm volatile("s_waitcnt vmcnt(0)" ::: "memory");
    asm volatile("s_barrier" ::: "memory");
    const int buf = t & 1;
    bf16x8 af[4][2], bfr[3][2];
#pragma unroll
    for (int m = 0; m < 4; ++m) {
      int row = wm * 64 + m * 16 + l15;
#pragma unroll
      for (int ks = 0; ks < 2; ++ks)
        af[m][ks] = *(const bf16x8*)&As[buf][row * 64 + (((ks * 4 + lhi) ^ (row & 7)) * 8)];
    }
#pragma unroll
    for (int n = 0; n < 3; ++n) {
      int row = wn * 48 + n * 16 + l15;
#pragma unroll
      for (int ks = 0; ks < 2; ++ks)
        bfr[n][ks] = *(const bf16x8*)&Bs[buf][row * 64 + (((ks * 4 + lhi) ^ (row & 7)) * 8)];
    }
    asm volatile("s_waitcnt lgkmcnt(0)" ::: "memory");
    asm volatile("s_barrier" ::: "memory");
    if (t + 2 < 12) stage((t + 2) * 64, buf);
    __builtin_amdgcn_s_setprio(1);
#pragma unroll
    for (int ks = 0; ks < 2; ++ks)
#pragma unroll
      for (int m = 0; m < 4; ++m)
#pragma unroll
        for (int n = 0; n < 3; ++n) {
          if (z2)
            acc[m][n] = __builtin_amdgcn_mfma_f32_16x16x32_bf16(bfr[n][ks], af[m][ks], acc[m][n], 0, 0, 0);
          else
            acc[m][n] = __builtin_amdgcn_mfma_f32_16x16x32_bf16(af[m][ks], bfr[n][ks], acc[m][n], 0, 0, 0);
        }
    __builtin_amdgcn_s_setprio(0);
  }

  if (!z2) {
#pragma unroll
    for (int m = 0; m < 4; ++m) {
#pragma unroll
      for (int r = 0; r < 4; ++r) {
        int row = m0 + wm * 64 + m * 16 + lhi * 4 + r;
        int bb = row >> 12, s = row & 4095;
#pragma unroll
        for (int n = 0; n < 3; ++n) {
          int col = n0 + wn * 48 + n * 16 + l15;
          int hh = col >> 6, dk = col & 63;
          out[((size_t)(bb * NH + hh) * SS + s) * DKH + dk] = f2bf(acc[m][n][r]);
        }
      }
    }
  } else {
#pragma unroll
    for (int m = 0; m < 4; ++m) {
      int srow = m0 + wm * 64 + m * 16 + l15;
      int bb = srow >> 12, s = srow & 4095;
#pragma unroll
      for (int n = 0; n < 3; ++n) {
#pragma unroll
        for (int r = 0; r < 4; ++r) {
          int col = n0 + wn * 48 + n * 16 + lhi * 4 + r;
          int hh = col >> 6, dk = col & 63;
          out[((size_t)(bb * NH + hh) * DKH + dk) * SS + s] = f2bf(acc[m][n][r]);
        }
      }
    }
  }
}

// ---------------------------------------------------------------------------
// pack 32 f32 P-values into 4 PV B-fragments (proven mapping)
// ---------------------------------------------------------------------------
__device__ __forceinline__ void pack_pb(const f32x16& s0, const f32x16& s1, bf16x8* pb) {
#pragma unroll
  for (int h2 = 0; h2 < 2; ++h2) {
    unsigned c0a = cvt_pk_bf16(s0[8 * h2 + 0], s0[8 * h2 + 1]);
    unsigned c1a = cvt_pk_bf16(s0[8 * h2 + 2], s0[8 * h2 + 3]);
    unsigned c0b = cvt_pk_bf16(s0[8 * h2 + 4], s0[8 * h2 + 5]);
    unsigned c1b = cvt_pk_bf16(s0[8 * h2 + 6], s0[8 * h2 + 7]);
    plane32_swap(c0a, c0b);
    plane32_swap(c1a, c1b);
    union { unsigned u[4]; bf16x8 v; } f;
    f.u[0] = c0a; f.u[1] = c1a; f.u[2] = c0b; f.u[3] = c1b;
    pb[h2] = f.v;
  }
#pragma unroll
  for (int h2 = 0; h2 < 2; ++h2) {
    unsigned c0a = cvt_pk_bf16(s1[8 * h2 + 0], s1[8 * h2 + 1]);
    unsigned c1a = cvt_pk_bf16(s1[8 * h2 + 2], s1[8 * h2 + 3]);
    unsigned c0b = cvt_pk_bf16(s1[8 * h2 + 4], s1[8 * h2 + 5]);
    unsigned c1b = cvt_pk_bf16(s1[8 * h2 + 6], s1[8 * h2 + 7]);
    plane32_swap(c0a, c0b);
    plane32_swap(c1a, c1b);
    union { unsigned u[4]; bf16x8 v; } f;
    f.u[0] = c0a; f.u[1] = c1a; f.u[2] = c0b; f.u[3] = c1b;
    pb[2 + h2] = f.v;
  }
}

__device__ __forceinline__ float tree16(const f32x16& v) {
  float a = (v[0] + v[1]) + (v[2] + v[3]);
  float b = (v[4] + v[5]) + (v[6] + v[7]);
  float c = (v[8] + v[9]) + (v[10] + v[11]);
  float d = (v[12] + v[13]) + (v[14] + v[15]);
  return (a + b) + (c + d);
}

// ---------------------------------------------------------------------------
// Flash attention v12: split-KV x2 ACROSS BLOCKS (global bf16 partials).
// Block = 4 waves x 32q = 128q sharing one dbuf K+V tile (32 KB LDS);
// r6-proven sync (vmcnt(0) + 1 barrier per iter, prefetch in flight).
// No-max softmax => partials sum exactly; combine kernel normalizes.
// grid (32,24,2) = 1536 blocks, XCD-swizzled; launch_bounds(256,4) ->
// <=128 VGPR (r2-identical body measured 76) -> 4 blocks/CU = 16 waves/CU.
// ---------------------------------------------------------------------------
__global__ __launch_bounds__(256, 4) void flash_attn(
    const unsigned short* __restrict__ Qp, const unsigned short* __restrict__ Kp,
    const unsigned short* __restrict__ Vt, unsigned short* __restrict__ Opart,
    float* __restrict__ Lpart) {
  __shared__ unsigned short KV[2][8192];  // [buf][K 64x64 | V^T 64x64] 32 KB
  const int tid = threadIdx.x;
  const int lane = tid & 63, wave = tid >> 6;
  const int ql = lane & 31, hi = lane >> 5;

  int fid = blockIdx.x + (blockIdx.y << 5) + (blockIdx.z << 9) + (blockIdx.z << 8);  // x + 32y + 768z
  int nid = (fid & 7) * 192 + (fid >> 3);
  const int qb = nid & 31;
  const int rem = nid >> 5;  // 0..47
  const int bh = rem % 24, split = rem / 24;
  const int b = bh / NH, h = bh % NH;
  const int q0w = qb * 128 + wave * 32;
  const int kvbase = split * (SS / 2);

  bf16x8 qf[4];
  {
    const unsigned short* qp = Qp + ((size_t)bh * SS + q0w + ql) * DKH;
#pragma unroll
    for (int s = 0; s < 4; ++s)
      qf[s] = *(const bf16x8*)(qp + s * 16 + hi * 8);
  }

  const unsigned short* gK = Kp + (size_t)bh * SS * DKH;
  const unsigned short* gV = Vt + (size_t)bh * DKH * SS;
  const int lrow = lane >> 3;
  const int sch = ((lane & 7) ^ lrow) * 8;  // pre-swizzled source chunk
  const int xs = (ql & 7) << 3;             // read-side swizzle

  // stage K+V tile: per wave 2 K + 2 V gload16 (4 waves cover 64 rows each)
  auto stage = [&](int kv0, int buf) {
#pragma unroll
    for (int i = 0; i < 2; ++i) {
      int r = wave * 16 + i * 8;
      gload16(gK + (size_t)(kv0 + r + lrow) * DKH + sch, &KV[buf][r * 64]);
      gload16(gV + (size_t)(r + lrow) * SS + kv0 + sch, &KV[buf][4096 + r * 64]);
    }
  };

  stage(kvbase, 0);

  f32x16 oA = {}, oB = {};
  float lp = 0.f;
  const f32x16 zc = {};

  for (int it = 0; it < 32; ++it) {
    asm volatile("s_waitcnt vmcnt(0)" ::: "memory");
    __builtin_amdgcn_s_barrier();
    __builtin_amdgcn_sched_barrier(0);
    const int buf = it & 1;
    if (it + 1 < 32) stage(kvbase + (it + 1) * 64, buf ^ 1);  // stays in flight
    const unsigned short* Ks = &KV[buf][0];
    const unsigned short* Vs = &KV[buf][4096];

    // S^T = K·Q^T (32q), first slice with hoisted zero C
    f32x16 s0, s1;
    __builtin_amdgcn_s_setprio(1);
    {
      bf16x8 ka0 = *(const bf16x8*)&Ks[ql * 64 + ((hi * 8) ^ xs)];
      bf16x8 ka1 = *(const bf16x8*)&Ks[(32 + ql) * 64 + ((hi * 8) ^ xs)];
      s0 = __builtin_amdgcn_mfma_f32_32x32x16_bf16(ka0, qf[0], zc, 0, 0, 0);
      s1 = __builtin_amdgcn_mfma_f32_32x32x16_bf16(ka1, qf[0], zc, 0, 0, 0);
    }
#pragma unroll
    for (int s = 1; s < 4; ++s) {
      bf16x8 ka0 = *(const bf16x8*)&Ks[ql * 64 + ((s * 16 + hi * 8) ^ xs)];
      bf16x8 ka1 = *(const bf16x8*)&Ks[(32 + ql) * 64 + ((s * 16 + hi * 8) ^ xs)];
      s0 = __builtin_amdgcn_mfma_f32_32x32x16_bf16(ka0, qf[s], s0, 0, 0, 0);
      s1 = __builtin_amdgcn_mfma_f32_32x32x16_bf16(ka1, qf[s], s1, 0, 0, 0);
    }
    __builtin_amdgcn_s_setprio(0);

    // P = exp2(S) (scores bounded; exp2-domain folded into wq)
#pragma unroll
    for (int r = 0; r < 16; ++r) s0[r] = fast_exp2(s0[r]);
#pragma unroll
    for (int r = 0; r < 16; ++r) s1[r] = fast_exp2(s1[r]);
    lp += tree16(s0) + tree16(s1);

    bf16x8 pb[4];
    pack_pb(s0, s1, pb);

    // O^T += V^T · P^T
    __builtin_amdgcn_s_setprio(1);
#pragma unroll
    for (int ks = 0; ks < 4; ++ks) {
      bf16x8 va0 = *(const bf16x8*)&Vs[ql * 64 + ((ks * 16 + hi * 8) ^ xs)];
      bf16x8 va1 = *(const bf16x8*)&Vs[(32 + ql) * 64 + ((ks * 16 + hi * 8) ^ xs)];
      oA = __builtin_amdgcn_mfma_f32_32x32x16_bf16(va0, pb[ks], oA, 0, 0, 0);
      oB = __builtin_amdgcn_mfma_f32_32x32x16_bf16(va1, pb[ks], oB, 0, 0, 0);
    }
    __builtin_amdgcn_s_setprio(0);
  }

  // epilogue: RAW partial O (bf16) + partial l (f32)
  float l = lp + __shfl_xor(lp, 32);
  unsigned short* orow = Opart + ((size_t)(split * 24 + bh) * SS + q0w + ql) * DKH;
#pragma unroll
  for (int g = 0; g < 4; ++g) {
    int d0 = g * 8 + hi * 4;
    *(unsigned*)&orow[d0]          = cvt_pk_bf16(oA[4 * g + 0], oA[4 * g + 1]);
    *(unsigned*)&orow[d0 + 2]      = cvt_pk_bf16(oA[4 * g + 2], oA[4 * g + 3]);
    *(unsigned*)&orow[32 + d0]     = cvt_pk_bf16(oB[4 * g + 0], oB[4 * g + 1]);
    *(unsigned*)&orow[32 + d0 + 2] = cvt_pk_bf16(oB[4 * g + 2], oB[4 * g + 3]);
  }
  if (hi == 0) Lpart[(size_t)(split * 24 + bh) * SS + q0w + ql] = l;
}

// ---------------------------------------------------------------------------
// Combine: attn[b][s][h*64+d] = (O0+O1) / (l0+l1). 8 bf16 per thread.
// ---------------------------------------------------------------------------
__global__ __launch_bounds__(256) void combine(
    const unsigned short* __restrict__ Opart, const float* __restrict__ Lpart,
    unsigned short* __restrict__ attn) {
  int gid = blockIdx.x * 256 + threadIdx.x;  // 786432
  size_t e = (size_t)gid * 8;
  int bhq = gid >> 3;
  const unsigned short* O1 = Opart + (size_t)24 * SS * DKH;
  const float* L1 = Lpart + (size_t)24 * SS;
  float inv = 1.0f / (Lpart[bhq] + L1[bhq]);
  uint4 a = *(const uint4*)(Opart + e);
  uint4 c = *(const uint4*)(O1 + e);
  const unsigned* pa = (const unsigned*)&a;
  const unsigned* pc = (const unsigned*)&c;
  union { unsigned u[4]; uint4 v; } o;
#pragma unroll
  for (int i = 0; i < 4; ++i) {
    union { unsigned v; float f; } lo0, hi0, lo1, hi1;
    lo0.v = (pa[i] & 0xffffu) << 16; hi0.v = pa[i] & 0xffff0000u;
    lo1.v = (pc[i] & 0xffffu) << 16; hi1.v = pc[i] & 0xffff0000u;
    o.u[i] = pkbf2((lo0.f + lo1.f) * inv, (hi0.f + hi1.f) * inv);
  }
  int bh = bhq >> 12, q = bhq & 4095;
  int b = bh / NH, h = bh % NH;
  int d0 = (gid & 7) * 8;
  *(uint4*)(attn + ((size_t)b * SS + q) * DM + h * DKH + d0) = o.v;
}

// ---------------------------------------------------------------------------
// Output GEMM (unchanged, proven).
// ---------------------------------------------------------------------------
__global__ __launch_bounds__(256, 2) void out_gemm(
    const unsigned short* __restrict__ A, const unsigned short* __restrict__ Wt,
    float* __restrict__ out) {
  __shared__ unsigned short As[2][64 * 64];
  __shared__ unsigned short Bs[2][128 * 64];
  const int tid = threadIdx.x;
  const int lane = tid & 63, wave = tid >> 6;
  const int wm = wave >> 1, wn = wave & 1;
  const int l15 = lane & 15, lhi = lane >> 4;
  const int lrow = lane >> 3;
  const int schunk = (lane & 7) ^ lrow;

  int fid = blockIdx.x + 6 * blockIdx.y;
  int nid = (fid & 7) * 96 + (fid >> 3);
  const int bx = nid % 6, by = nid / 6;
  const int m0 = by * 64, n0 = bx * 128;

  auto stage = [&](int k0, int buf) {
#pragma unroll
    for (int i = 0; i < 4; ++i) {
      int r = wave * 32 + i * 8;
      gload16(Wt + (size_t)(n0 + r + lrow) * DM + k0 + schunk * 8, &Bs[buf][r * 64]);
    }
#pragma unroll
    for (int i = 0; i < 2; ++i) {
      int r = wave * 16 + i * 8;
      gload16(A + (size_t)(m0 + r + lrow) * DM + k0 + schunk * 8, &As[buf][r * 64]);
    }
  };

  f32x4 acc[2][4] = {};
  stage(0, 0);
  stage(64, 1);

  for (int t = 0; t < 12; ++t) {
    if (t < 11) asm volatile("s_waitcnt vmcnt(6)" ::: "memory");
    else        asm volatile("s_waitcnt vmcnt(0)" ::: "memory");
    asm volatile("s_barrier" ::: "memory");
    const int buf = t & 1;
    bf16x8 af[2][2], bfr[4][2];
#pragma unroll
    for (int m = 0; m < 2; ++m) {
      int row = wm * 32 + m * 16 + l15;
#pragma unroll
      for (int ks = 0; ks < 2; ++ks)
        af[m][ks] = *(const bf16x8*)&As[buf][row * 64 + (((ks * 4 + lhi) ^ (row & 7)) * 8)];
    }
#pragma unroll
    for (int n = 0; n < 4; ++n) {
      int row = wn * 64 + n * 16 + l15;
#pragma unroll
      for (int ks = 0; ks < 2; ++ks)
        bfr[n][ks] = *(const bf16x8*)&Bs[buf][row * 64 + (((ks * 4 + lhi) ^ (row & 7)) * 8)];
    }
    asm volatile("s_waitcnt lgkmcnt(0)" ::: "memory");
    asm volatile("s_barrier" ::: "memory");
    if (t + 2 < 12) stage((t + 2) * 64, buf);
    __builtin_amdgcn_s_setprio(1);
#pragma unroll
    for (int ks = 0; ks < 2; ++ks)
#pragma unroll
      for (int m = 0; m < 2; ++m)
#pragma unroll
        for (int n = 0; n < 4; ++n)
          acc[m][n] = __builtin_amdgcn_mfma_f32_16x16x32_bf16(af[m][ks], bfr[n][ks], acc[m][n], 0, 0, 0);
    __builtin_amdgcn_s_setprio(0);
  }

#pragma unroll
  for (int m = 0; m < 2; ++m)
#pragma unroll
    for (int r = 0; r < 4; ++r) {
      int row = m0 + wm * 32 + m * 16 + lhi * 4 + r;
#pragma unroll
      for (int n = 0; n < 4; ++n) {
        int col = n0 + wn * 64 + n * 16 + l15;
        out[(size_t)row * DM + col] = acc[m][n][r];
      }
    }
}

// ---------------------------------------------------------------------------
extern "C" void kernel_launch(void* const* d_in, const int* in_sizes, int n_in,
                              void* d_out, int out_size, void* d_ws, size_t ws_size,
                              hipStream_t stream) {
  const float* Q  = (const float*)d_in[0];
  const float* K  = (const float*)d_in[1];
  const float* V  = (const float*)d_in[2];
  const float* WQ = (const float*)d_in[3];
  const float* WK = (const float*)d_in[4];
  const float* WV = (const float*)d_in[5];
  const float* WO = (const float*)d_in[6];
  char* ws = (char*)d_ws;

  const size_t WSZ = (size_t)DM * DM * 2;
  const size_t ABF = (size_t)2 * SS * DM * 2;  // 12,582,912 bytes
  unsigned short* w_base  = (unsigned short*)(ws);
  unsigned short* wo_t    = (unsigned short*)(ws + 3 * WSZ);
  unsigned short* qkv_bf  = (unsigned short*)(ws + 4 * WSZ);
  unsigned short* p_base  = (unsigned short*)(ws + 4 * WSZ + 3 * ABF);
  unsigned short* q_p  = p_base;
  unsigned short* k_p  = p_base + ABF / 2;
  unsigned short* v_t  = p_base + ABF;
  unsigned short* attn = p_base + 3 * (ABF / 2);
  // partials alias the dead qkv_bf region (25.2 MB + 1.6 MB <= 37.7 MB)
  unsigned short* opart = qkv_bf;
  float* lpart = (float*)(ws + 4 * WSZ + 2 * ABF);

  prep<<<9216 + 2304, 256, 0, stream>>>(
      Q, K, V, WQ, WK, WV, WO, qkv_bf,
      w_base, w_base + WSZ / 2, w_base + WSZ, wo_t);

  proj_gemm3<<<dim3(8, 64, 3), 256, 0, stream>>>(qkv_bf, w_base, p_base);

  flash_attn<<<dim3(32, 24, 2), 256, 0, stream>>>(q_p, k_p, v_t, opart, lpart);

  combine<<<3072, 256, 0, stream>>>(opart, lpart, attn);

  out_gemm<<<dim3(6, 128), 256, 0, stream>>>(attn, wo_t, (float*)d_out);
}